// Round 1
// baseline (312.668 us; speedup 1.0000x reference)
//
#include <hip/hip_runtime.h>

#define B_ 4
#define C_ 256
#define N_ 4096
#define CPG_ 16
#define SCALE_ 0.0625f

typedef __attribute__((ext_vector_type(8))) short short8;
typedef __attribute__((ext_vector_type(4))) float f32x4;

static __device__ __forceinline__ short f2bf(float f) {
  union { float f; unsigned u; } v; v.f = f;
  unsigned r = v.u + 0x7FFFu + ((v.u >> 16) & 1u);
  return (short)(r >> 16);
}

static __device__ __forceinline__ f32x4 mfma16(short8 a, short8 b, f32x4 c) {
  return __builtin_amdgcn_mfma_f32_16x16x32_bf16(a, b, c, 0, 0, 0);
}

// ---------------- GroupNorm ----------------
__global__ __launch_bounds__(256) void gn_stats(const float* __restrict__ x,
                                                float* __restrict__ stats) {
  int bg = blockIdx.x;                       // b*16+g ; group channels are contiguous
  const float* xp = x + (long)bg * (CPG_ * N_);
  int t = threadIdx.x;
  float s = 0.f, ss = 0.f;
  for (int e = t; e < CPG_ * N_; e += 256) { float v = xp[e]; s += v; ss += v * v; }
  __shared__ float rs[256], rq[256];
  rs[t] = s; rq[t] = ss; __syncthreads();
  for (int off = 128; off > 0; off >>= 1) {
    if (t < off) { rs[t] += rs[t + off]; rq[t] += rq[t + off]; }
    __syncthreads();
  }
  if (t == 0) {
    float inv = 1.f / (float)(CPG_ * N_);
    float mean = rs[0] * inv;
    float var = rq[0] * inv - mean * mean;
    stats[bg * 2] = mean;
    stats[bg * 2 + 1] = rsqrtf(var + 1e-6f);
  }
}

// writes hn transposed: hn[b][i][c] bf16 (K-contiguous for MFMA fragments)
__global__ __launch_bounds__(256) void gn_norm(const float* __restrict__ x,
                                               const float* __restrict__ gamma,
                                               const float* __restrict__ beta,
                                               const float* __restrict__ stats,
                                               short* __restrict__ hn) {
  int ic = blockIdx.x, g = blockIdx.y, b = blockIdx.z;
  float mean = stats[(b * 16 + g) * 2];
  float rstd = stats[(b * 16 + g) * 2 + 1];
  int t = threadIdx.x;
  int i = ic * 256 + t;
  __shared__ short Ls[16][256];
#pragma unroll
  for (int cl = 0; cl < 16; cl++) {
    int c = g * 16 + cl;
    float v = x[((long)(b * 256 + c)) * N_ + i];
    Ls[cl][t] = f2bf((v - mean) * rstd * gamma[c] + beta[c]);
  }
  __syncthreads();
  short8 v0, v1;
#pragma unroll
  for (int q = 0; q < 8; q++) { v0[q] = Ls[q][t]; v1[q] = Ls[8 + q][t]; }
  short* dst = hn + ((long)b * N_ + ic * 256 + t) * C_ + g * 16;
  *(short8*)dst = v0;
  *(short8*)(dst + 8) = v1;
}

// ---------------- weight cast fp32->bf16 ----------------
__global__ __launch_bounds__(256) void cast_w(const float* __restrict__ wq,
                                              const float* __restrict__ wk,
                                              const float* __restrict__ wv,
                                              const float* __restrict__ wp,
                                              short* __restrict__ out) {
  int idx = blockIdx.x * 256 + threadIdx.x;       // 4*65536
  int which = idx >> 16, e = idx & 65535;
  const float* src = which == 0 ? wq : which == 1 ? wk : which == 2 ? wv : wp;
  out[(which << 16) + e] = f2bf(src[e]);
}

// ---------------- GEMM: C[M][Ndim] = A[M][K] * Bw[Ndim][K]^T (+bias, +resid) ----
// All operands bf16 (short), K-contiguous row-major. 128x128 tile, 4 waves, BK=32.
template <bool STORE_T, bool BIAS_ROW, bool RESID, typename OUT_T>
__global__ __launch_bounds__(256) void gemm_nt(const short* __restrict__ A,
                                               const short* __restrict__ Bw,
                                               const float* __restrict__ bias,
                                               const float* __restrict__ resid,
                                               OUT_T* __restrict__ Cout,
                                               int M, int Ndim, int K,
                                               long sA, long sB, long sC) {
  __shared__ short As[128 * 32];
  __shared__ short Bs[128 * 32];
  const int bz = blockIdx.z;
  const int n0 = blockIdx.x * 128;
  const int m0 = blockIdx.y * 128;
  const int t = threadIdx.x;
  const int lane = t & 63, w = t >> 6;
  const int wm = (w >> 1) * 64, wn = (w & 1) * 64;
  const short* Ab = A + bz * sA;
  const short* Bb = Bw + bz * sB;

  f32x4 acc[4][4];
#pragma unroll
  for (int m = 0; m < 4; m++)
#pragma unroll
    for (int n = 0; n < 4; n++) acc[m][n] = (f32x4)0.f;

  const int r0 = t >> 2;                  // staging row (64 rows / step)
  const int c0 = (t & 3) * 16;            // staging byte-col within 64B row
  const int wcol = (c0 ^ ((r0 & 3) << 4)) >> 1;  // swizzled short offset
  const int g16 = (lane >> 4) * 16;       // frag k byte-offset

  for (int kt = 0; kt < K; kt += 32) {
    short8 ra0 = *(const short8*)(Ab + (long)(m0 + r0) * K + kt + (c0 >> 1));
    short8 ra1 = *(const short8*)(Ab + (long)(m0 + r0 + 64) * K + kt + (c0 >> 1));
    short8 rb0 = *(const short8*)(Bb + (long)(n0 + r0) * K + kt + (c0 >> 1));
    short8 rb1 = *(const short8*)(Bb + (long)(n0 + r0 + 64) * K + kt + (c0 >> 1));
    __syncthreads();
    *(short8*)(As + r0 * 32 + wcol) = ra0;
    *(short8*)(As + (r0 + 64) * 32 + wcol) = ra1;   // (r0+64)&3 == r0&3
    *(short8*)(Bs + r0 * 32 + wcol) = rb0;
    *(short8*)(Bs + (r0 + 64) * 32 + wcol) = rb1;
    __syncthreads();
    short8 af[4], bf[4];
#pragma unroll
    for (int m = 0; m < 4; m++) {
      int row = wm + m * 16 + (lane & 15);
      af[m] = *(const short8*)(As + row * 32 + ((g16 ^ ((row & 3) << 4)) >> 1));
    }
#pragma unroll
    for (int n = 0; n < 4; n++) {
      int row = wn + n * 16 + (lane & 15);
      bf[n] = *(const short8*)(Bs + row * 32 + ((g16 ^ ((row & 3) << 4)) >> 1));
    }
#pragma unroll
    for (int m = 0; m < 4; m++)
#pragma unroll
      for (int n = 0; n < 4; n++) acc[m][n] = mfma16(af[m], bf[n], acc[m][n]);
  }

#pragma unroll
  for (int m = 0; m < 4; m++)
#pragma unroll
    for (int n = 0; n < 4; n++)
#pragma unroll
      for (int r = 0; r < 4; r++) {
        int row = m0 + wm + m * 16 + ((lane >> 4) << 2) + r;
        int col = n0 + wn + n * 16 + (lane & 15);
        float vv = acc[m][n][r];
        vv += BIAS_ROW ? bias[row] : bias[col];
        if (RESID) vv += resid[bz * sC + (long)row * Ndim + col];
        long co = STORE_T ? (bz * sC + (long)col * M + row)
                          : (bz * sC + (long)row * Ndim + col);
        if constexpr (sizeof(OUT_T) == 2) ((short*)Cout)[co] = f2bf(vv);
        else ((float*)Cout)[co] = vv;
      }
}

// ---------------- Flash attention: per batch, Q-tile 64 rows, TJ=64 ----------
// qT,kT: [B][N][C] bf16 ; vM: [B][C][N] bf16 ; hT out: [B][N][C] bf16
__global__ __launch_bounds__(256) void attn_kernel(const short* __restrict__ qT,
                                                   const short* __restrict__ kT,
                                                   const short* __restrict__ vM,
                                                   short* __restrict__ hT) {
  __shared__ short Ks[64 * 256];   // rows j (512B), XOR-swizzled
  __shared__ short Vs[256 * 64];   // rows c (128B), XOR-swizzled
  __shared__ short Ps[4][16 * 64]; // per-wave P tile (128B rows), swizzled
  const int b = blockIdx.y;
  const int i0 = blockIdx.x * 64;
  const int t = threadIdx.x, lane = t & 63, w = t >> 6;
  const short* qb = qT + (long)b * N_ * C_;
  const short* kb = kT + (long)b * N_ * C_;
  const short* vb = vM + (long)b * C_ * N_;

  // preload this wave's 16 Q rows as A-fragments (32 VGPRs)
  short8 qf[8];
  {
    const short* qp = qb + (long)(i0 + w * 16 + (lane & 15)) * C_ + (lane >> 4) * 8;
#pragma unroll
    for (int kk = 0; kk < 8; kk++) qf[kk] = *(const short8*)(qp + kk * 32);
  }
  float m_run[4], l_run[4];
#pragma unroll
  for (int r = 0; r < 4; r++) { m_run[r] = -1e30f; l_run[r] = 0.f; }
  f32x4 acco[16];
#pragma unroll
  for (int n = 0; n < 16; n++) acco[n] = (f32x4)0.f;

  short* Psw = &Ps[w][0];

  for (int j0 = 0; j0 < N_; j0 += 64) {
    __syncthreads();  // previous iter done reading Ks/Vs
    // stage K tile [64][256] (coalesced read, swizzled LDS write)
#pragma unroll
    for (int s = 0; s < 8; s++) {
      int flat = t * 16 + s * 4096;
      int row = flat >> 9, colB = flat & 511;
      short8 val = *(const short8*)(kb + (long)(j0 + row) * C_ + (colB >> 1));
      *(short8*)((char*)Ks + row * 512 + (colB ^ ((row & 7) << 4))) = val;
    }
    // stage V tile [256 c][64 j]
#pragma unroll
    for (int s = 0; s < 8; s++) {
      int flat = t * 16 + s * 4096;
      int row = flat >> 7, colB = flat & 127;
      short8 val = *(const short8*)(vb + (long)row * N_ + j0 + (colB >> 1));
      *(short8*)((char*)Vs + row * 128 + (colB ^ ((row & 7) << 4))) = val;
    }
    __syncthreads();

    // S = Q K^T  (16 x 64 per wave)
    f32x4 accs[4];
#pragma unroll
    for (int n = 0; n < 4; n++) accs[n] = (f32x4)0.f;
#pragma unroll
    for (int kk = 0; kk < 8; kk++)
#pragma unroll
      for (int n = 0; n < 4; n++) {
        int row = n * 16 + (lane & 15);
        int colB = ((kk * 32 + (lane >> 4) * 8) * 2) ^ ((row & 7) << 4);
        short8 bfr = *(const short8*)((char*)Ks + row * 512 + colB);
        accs[n] = mfma16(qf[kk], bfr, accs[n]);
      }

    // online softmax (rows live as (lane>>4)*4+r ; cols across lane&15 and n)
#pragma unroll
    for (int r = 0; r < 4; r++) {
      float s0 = accs[0][r] * SCALE_;
      float s1 = accs[1][r] * SCALE_;
      float s2 = accs[2][r] * SCALE_;
      float s3 = accs[3][r] * SCALE_;
      float mx = fmaxf(fmaxf(s0, s1), fmaxf(s2, s3));
      mx = fmaxf(mx, __shfl_xor(mx, 1));
      mx = fmaxf(mx, __shfl_xor(mx, 2));
      mx = fmaxf(mx, __shfl_xor(mx, 4));
      mx = fmaxf(mx, __shfl_xor(mx, 8));
      float mnew = fmaxf(m_run[r], mx);
      float corr = __expf(m_run[r] - mnew);
      float p0 = __expf(s0 - mnew), p1 = __expf(s1 - mnew);
      float p2 = __expf(s2 - mnew), p3 = __expf(s3 - mnew);
      float rsum = p0 + p1 + p2 + p3;
      rsum += __shfl_xor(rsum, 1);
      rsum += __shfl_xor(rsum, 2);
      rsum += __shfl_xor(rsum, 4);
      rsum += __shfl_xor(rsum, 8);
      l_run[r] = l_run[r] * corr + rsum;
      m_run[r] = mnew;
#pragma unroll
      for (int n = 0; n < 16; n++) acco[n][r] *= corr;
      int rowl = (lane >> 4) * 4 + r;
      char* pr = (char*)Psw + rowl * 128;
      int cb = (lane & 15) * 2;
      int sw = (rowl & 7) << 4;
      *(short*)(pr + (cb ^ sw)) = f2bf(p0);
      *(short*)(pr + ((cb + 32) ^ sw)) = f2bf(p1);
      *(short*)(pr + ((cb + 64) ^ sw)) = f2bf(p2);
      *(short*)(pr + ((cb + 96) ^ sw)) = f2bf(p3);
    }
    // per-wave LDS write->read fence (Ps is wave-private; no block barrier needed)
    asm volatile("s_waitcnt lgkmcnt(0)" ::: "memory");

    // O += P * V^T   (A = P from Ps, B = Vs)
#pragma unroll
    for (int kk2 = 0; kk2 < 2; kk2++) {
      int rowl = lane & 15;
      int colB = ((kk2 * 32 + (lane >> 4) * 8) * 2) ^ ((rowl & 7) << 4);
      short8 pa = *(const short8*)((char*)Psw + rowl * 128 + colB);
#pragma unroll
      for (int n = 0; n < 16; n++) {
        int rowc = n * 16 + (lane & 15);
        int cB = ((kk2 * 32 + (lane >> 4) * 8) * 2) ^ ((rowc & 7) << 4);
        short8 vfr = *(const short8*)((char*)Vs + rowc * 128 + cB);
        acco[n] = mfma16(pa, vfr, acco[n]);
      }
    }
  }

#pragma unroll
  for (int n = 0; n < 16; n++)
#pragma unroll
    for (int r = 0; r < 4; r++) {
      int i = i0 + w * 16 + ((lane >> 4) << 2) + r;
      int c = n * 16 + (lane & 15);
      hT[((long)b * N_ + i) * C_ + c] = f2bf(acco[n][r] / l_run[r]);
    }
}

// ---------------- launch ----------------
extern "C" void kernel_launch(void* const* d_in, const int* in_sizes, int n_in,
                              void* d_out, int out_size, void* d_ws, size_t ws_size,
                              hipStream_t stream) {
  const float* x = (const float*)d_in[0];
  const float* gamma = (const float*)d_in[1];
  const float* beta = (const float*)d_in[2];
  const float* wq = (const float*)d_in[3];
  const float* bq = (const float*)d_in[4];
  const float* wk = (const float*)d_in[5];
  const float* bk = (const float*)d_in[6];
  const float* wv = (const float*)d_in[7];
  const float* bv = (const float*)d_in[8];
  const float* wp = (const float*)d_in[9];
  const float* bp = (const float*)d_in[10];

  char* ws = (char*)d_ws;
  short* hn = (short*)ws;                                   // 8MB, reused as hT after attn
  short* qT = (short*)(ws + (size_t)8 * 1024 * 1024);       // 8MB
  short* kT = (short*)(ws + (size_t)16 * 1024 * 1024);      // 8MB
  short* vb = (short*)(ws + (size_t)24 * 1024 * 1024);      // 8MB
  short* wqb = (short*)(ws + (size_t)32 * 1024 * 1024);     // 4 x 128KB
  short* wkb = wqb + 65536;
  short* wvb = wkb + 65536;
  short* wpb = wvb + 65536;
  float* stats = (float*)(ws + (size_t)33 * 1024 * 1024);   // 64 x 2 floats

  gn_stats<<<64, 256, 0, stream>>>(x, stats);
  gn_norm<<<dim3(16, 16, 4), 256, 0, stream>>>(x, gamma, beta, stats, hn);
  cast_w<<<1024, 256, 0, stream>>>(wq, wk, wv, wp, wqb);

  const long sNC = (long)N_ * C_;
  // qT[i][o] = hn[i][:] . wq[o][:] + bq[o]
  gemm_nt<false, false, false, short><<<dim3(2, 32, 4), 256, 0, stream>>>(
      hn, wqb, bq, nullptr, qT, N_, C_, C_, sNC, 0, sNC);
  gemm_nt<false, false, false, short><<<dim3(2, 32, 4), 256, 0, stream>>>(
      hn, wkb, bk, nullptr, kT, N_, C_, C_, sNC, 0, sNC);
  // v[o][i] (transposed store)
  gemm_nt<true, false, false, short><<<dim3(2, 32, 4), 256, 0, stream>>>(
      hn, wvb, bv, nullptr, vb, N_, C_, C_, sNC, 0, sNC);

  attn_kernel<<<dim3(64, 4), 256, 0, stream>>>(qT, kT, vb, hn /* hT out */);

  // out[o][i] = x[o][i] + wp[o][:] . hT[i][:] + bp[o]
  gemm_nt<false, true, true, float><<<dim3(32, 2, 4), 256, 0, stream>>>(
      wpb, hn, bp, x, (float*)d_out, C_, N_, C_, 0, sNC, sNC);
}

// Round 2
// 298.958 us; speedup vs baseline: 1.0459x; 1.0459x over previous
//
#include <hip/hip_runtime.h>

#define B_ 4
#define C_ 256
#define N_ 4096
#define CPG_ 16
#define K2_ 0.09016844f   /* 0.0625 * log2(e) */
#define THR_ 100.0f       /* defer-max threshold in raw-score units: p <= 2^(100*K2) ~ 512 */

typedef __attribute__((ext_vector_type(8))) short short8;
typedef __attribute__((ext_vector_type(4))) float f32x4;

static __device__ __forceinline__ short f2bf(float f) {
  union { float f; unsigned u; } v; v.f = f;
  unsigned r = v.u + 0x7FFFu + ((v.u >> 16) & 1u);
  return (short)(r >> 16);
}
static __device__ __forceinline__ float bf2f(short s) {
  union { unsigned u; float f; } v; v.u = ((unsigned)(unsigned short)s) << 16;
  return v.f;
}
static __device__ __forceinline__ f32x4 mfma16(short8 a, short8 b, f32x4 c) {
  return __builtin_amdgcn_mfma_f32_16x16x32_bf16(a, b, c, 0, 0, 0);
}
static __device__ __forceinline__ void gload16(const void* g, void* l) {
  __builtin_amdgcn_global_load_lds(
      (const __attribute__((address_space(1))) unsigned int*)g,
      (__attribute__((address_space(3))) unsigned int*)l, 16, 0, 0);
}

// ---------------- GroupNorm ----------------
__global__ __launch_bounds__(256) void gn_stats(const float* __restrict__ x,
                                                float* __restrict__ stats) {
  int bg = blockIdx.x;
  const float* xp = x + (long)bg * (CPG_ * N_);
  int t = threadIdx.x;
  float s = 0.f, ss = 0.f;
  for (int e = t; e < CPG_ * N_; e += 256) { float v = xp[e]; s += v; ss += v * v; }
  __shared__ float rs[256], rq[256];
  rs[t] = s; rq[t] = ss; __syncthreads();
  for (int off = 128; off > 0; off >>= 1) {
    if (t < off) { rs[t] += rs[t + off]; rq[t] += rq[t + off]; }
    __syncthreads();
  }
  if (t == 0) {
    float inv = 1.f / (float)(CPG_ * N_);
    float mean = rs[0] * inv;
    float var = rq[0] * inv - mean * mean;
    stats[bg * 2] = mean;
    stats[bg * 2 + 1] = rsqrtf(var + 1e-6f);
  }
}

// writes hn transposed: hn[b][i][c] bf16
__global__ __launch_bounds__(256) void gn_norm(const float* __restrict__ x,
                                               const float* __restrict__ gamma,
                                               const float* __restrict__ beta,
                                               const float* __restrict__ stats,
                                               short* __restrict__ hn) {
  int ic = blockIdx.x, g = blockIdx.y, b = blockIdx.z;
  float mean = stats[(b * 16 + g) * 2];
  float rstd = stats[(b * 16 + g) * 2 + 1];
  int t = threadIdx.x;
  int i = ic * 256 + t;
  __shared__ short Ls[16][256];
#pragma unroll
  for (int cl = 0; cl < 16; cl++) {
    int c = g * 16 + cl;
    float v = x[((long)(b * 256 + c)) * N_ + i];
    Ls[cl][t] = f2bf((v - mean) * rstd * gamma[c] + beta[c]);
  }
  __syncthreads();
  short8 v0, v1;
#pragma unroll
  for (int q = 0; q < 8; q++) { v0[q] = Ls[q][t]; v1[q] = Ls[8 + q][t]; }
  short* dst = hn + ((long)b * N_ + ic * 256 + t) * C_ + g * 16;
  *(short8*)dst = v0;
  *(short8*)(dst + 8) = v1;
}

// ---------------- weight cast ----------------
__global__ __launch_bounds__(256) void cast_w(const float* __restrict__ wq,
                                              const float* __restrict__ wk,
                                              const float* __restrict__ wv,
                                              const float* __restrict__ wp,
                                              short* __restrict__ out) {
  int idx = blockIdx.x * 256 + threadIdx.x;
  int which = idx >> 16, e = idx & 65535;
  const float* src = which == 0 ? wq : which == 1 ? wk : which == 2 ? wv : wp;
  out[(which << 16) + e] = f2bf(src[e]);
}

// ---------------- fused QKV GEMM ----------------
// A = hn[b][N][256], W = wqkv[768][256]; q/k row-major [b][N][256], v transposed [b][256][N]
__global__ __launch_bounds__(256) void gemm_qkv(const short* __restrict__ hn,
                                                const short* __restrict__ wqkv,
                                                const float* __restrict__ bq,
                                                const float* __restrict__ bk,
                                                const float* __restrict__ bv,
                                                short* __restrict__ qT,
                                                short* __restrict__ kT,
                                                short* __restrict__ vbM) {
  __shared__ __align__(16) short As[128 * 32];
  __shared__ __align__(16) short Bs[128 * 32];
  const int bz = blockIdx.z;
  const int n0 = blockIdx.x * 128;   // within 768
  const int m0 = blockIdx.y * 128;   // within 4096
  const int t = threadIdx.x, lane = t & 63, w = t >> 6;
  const int wm = (w >> 1) * 64, wn = (w & 1) * 64;
  const short* Ab = hn + (long)bz * N_ * C_;
  f32x4 acc[4][4];
#pragma unroll
  for (int m = 0; m < 4; m++)
#pragma unroll
    for (int n = 0; n < 4; n++) acc[m][n] = (f32x4)0.f;
  const int g16 = (lane >> 4) * 16;

  for (int kt = 0; kt < 256; kt += 32) {
    __syncthreads();
#pragma unroll
    for (int s = 0; s < 2; s++) {
      int q = w * 2 + s;
      int flat = q * 1024 + lane * 16;
      int row = flat >> 6, c = flat & 63;
      int cs = c ^ ((row & 3) << 4);
      gload16((const char*)Ab + ((long)(m0 + row) * 256 + kt) * 2 + cs, (char*)As + q * 1024);
      gload16((const char*)wqkv + ((long)(n0 + row) * 256 + kt) * 2 + cs, (char*)Bs + q * 1024);
    }
    __syncthreads();
    short8 af[4], bf[4];
#pragma unroll
    for (int m = 0; m < 4; m++) {
      int row = wm + m * 16 + (lane & 15);
      af[m] = *(const short8*)(As + row * 32 + ((g16 ^ ((row & 3) << 4)) >> 1));
    }
#pragma unroll
    for (int n = 0; n < 4; n++) {
      int row = wn + n * 16 + (lane & 15);
      bf[n] = *(const short8*)(Bs + row * 32 + ((g16 ^ ((row & 3) << 4)) >> 1));
    }
#pragma unroll
    for (int m = 0; m < 4; m++)
#pragma unroll
      for (int n = 0; n < 4; n++) acc[m][n] = mfma16(af[m], bf[n], acc[m][n]);
  }

  int seg = n0 >> 8;
  const float* bias = seg == 0 ? bq : seg == 1 ? bk : bv;
#pragma unroll
  for (int m = 0; m < 4; m++)
#pragma unroll
    for (int n = 0; n < 4; n++)
#pragma unroll
      for (int r = 0; r < 4; r++) {
        int row = m0 + wm + m * 16 + ((lane >> 4) << 2) + r;
        int colg = n0 + wn + n * 16 + (lane & 15);
        int coll = colg & 255;
        float vv = acc[m][n][r] + bias[coll];
        if (seg == 2) vbM[(long)bz * N_ * C_ + (long)coll * N_ + row] = f2bf(vv);
        else (seg == 0 ? qT : kT)[(long)bz * N_ * C_ + (long)row * 256 + coll] = f2bf(vv);
      }
}

// ---------------- output projection GEMM (+bias row, +residual) ----------------
__global__ __launch_bounds__(256) void gemm_proj(const short* __restrict__ wp,
                                                 const short* __restrict__ hT,
                                                 const float* __restrict__ bp,
                                                 const float* __restrict__ x,
                                                 float* __restrict__ out) {
  __shared__ __align__(16) short As[128 * 32];
  __shared__ __align__(16) short Bs[128 * 32];
  const int bz = blockIdx.z;
  const int n0 = blockIdx.x * 128;   // pixels
  const int m0 = blockIdx.y * 128;   // channels
  const int t = threadIdx.x, lane = t & 63, w = t >> 6;
  const int wm = (w >> 1) * 64, wn = (w & 1) * 64;
  const short* Bb = hT + (long)bz * N_ * C_;
  f32x4 acc[4][4];
#pragma unroll
  for (int m = 0; m < 4; m++)
#pragma unroll
    for (int n = 0; n < 4; n++) acc[m][n] = (f32x4)0.f;
  const int g16 = (lane >> 4) * 16;

  for (int kt = 0; kt < 256; kt += 32) {
    __syncthreads();
#pragma unroll
    for (int s = 0; s < 2; s++) {
      int q = w * 2 + s;
      int flat = q * 1024 + lane * 16;
      int row = flat >> 6, c = flat & 63;
      int cs = c ^ ((row & 3) << 4);
      gload16((const char*)wp + ((long)(m0 + row) * 256 + kt) * 2 + cs, (char*)As + q * 1024);
      gload16((const char*)Bb + ((long)(n0 + row) * 256 + kt) * 2 + cs, (char*)Bs + q * 1024);
    }
    __syncthreads();
    short8 af[4], bf[4];
#pragma unroll
    for (int m = 0; m < 4; m++) {
      int row = wm + m * 16 + (lane & 15);
      af[m] = *(const short8*)(As + row * 32 + ((g16 ^ ((row & 3) << 4)) >> 1));
    }
#pragma unroll
    for (int n = 0; n < 4; n++) {
      int row = wn + n * 16 + (lane & 15);
      bf[n] = *(const short8*)(Bs + row * 32 + ((g16 ^ ((row & 3) << 4)) >> 1));
    }
#pragma unroll
    for (int m = 0; m < 4; m++)
#pragma unroll
      for (int n = 0; n < 4; n++) acc[m][n] = mfma16(af[m], bf[n], acc[m][n]);
  }

#pragma unroll
  for (int m = 0; m < 4; m++)
#pragma unroll
    for (int n = 0; n < 4; n++)
#pragma unroll
      for (int r = 0; r < 4; r++) {
        int row = m0 + wm + m * 16 + ((lane >> 4) << 2) + r;   // channel
        int col = n0 + wn + n * 16 + (lane & 15);              // pixel
        long idx = (long)bz * N_ * C_ + (long)row * N_ + col;
        out[idx] = acc[m][n][r] + bp[row] + x[idx];
      }
}

// ---------------- flash attention, split-j halves ----------------
// qT,kT: [B][N][C] bf16 ; vM: [B][C][N] bf16 ; Opart: [B][N][C] bf16 per half
__global__ __launch_bounds__(256) void attn_kernel(const short* __restrict__ qT,
                                                   const short* __restrict__ kT,
                                                   const short* __restrict__ vM,
                                                   short* __restrict__ O0,
                                                   short* __restrict__ O1,
                                                   float2* __restrict__ ml) {
  __shared__ __align__(16) short Ks[64 * 256];
  __shared__ __align__(16) short Vs[256 * 64];
  __shared__ __align__(16) short Ps[4][16 * 64];
  const int b = blockIdx.y;
  const int i0 = blockIdx.x * 64;
  const int half = blockIdx.z;
  const int jbase = half * (N_ / 2);
  const int t = threadIdx.x, lane = t & 63, w = t >> 6;
  const short* qb = qT + (long)b * N_ * C_;
  const char* kb = (const char*)(kT + (long)b * N_ * C_);
  const char* vbp = (const char*)(vM + (long)b * C_ * N_);

  short8 qf[8];
  {
    const short* qp = qb + (long)(i0 + w * 16 + (lane & 15)) * C_ + (lane >> 4) * 8;
#pragma unroll
    for (int kk = 0; kk < 8; kk++) qf[kk] = *(const short8*)(qp + kk * 32);
  }
  float m_run[4], l_run[4];
#pragma unroll
  for (int r = 0; r < 4; r++) { m_run[r] = -1e30f; l_run[r] = 0.f; }
  f32x4 acco[16];
#pragma unroll
  for (int n = 0; n < 16; n++) acco[n] = (f32x4)0.f;

  short* Psw = &Ps[w][0];

  for (int jt = 0; jt < N_ / 128; jt++) {
    const int j0 = jbase + jt * 64;
    __syncthreads();  // previous iter done reading Ks/Vs
    // stage K tile [64 j][512B] and V tile [256 c][128B], swizzled-source gload_lds
#pragma unroll
    for (int s = 0; s < 8; s++) {
      int q = w * 8 + s;
      int flat = q * 1024 + lane * 16;
      int rowk = flat >> 9, ck = flat & 511;
      gload16(kb + (long)(j0 + rowk) * 512 + (ck ^ ((rowk & 7) << 4)), (char*)Ks + q * 1024);
      int rowv = flat >> 7, cv = flat & 127;
      gload16(vbp + (long)rowv * (N_ * 2) + (long)j0 * 2 + (cv ^ ((rowv & 7) << 4)),
              (char*)Vs + q * 1024);
    }
    __syncthreads();  // compiler drains vmcnt before barrier

    // S = Q K^T (raw scores), 16 x 64 per wave
    f32x4 accs[4];
#pragma unroll
    for (int n = 0; n < 4; n++) accs[n] = (f32x4)0.f;
#pragma unroll
    for (int kk = 0; kk < 8; kk++)
#pragma unroll
      for (int n = 0; n < 4; n++) {
        int row = n * 16 + (lane & 15);
        int colB = ((kk * 32 + (lane >> 4) * 8) * 2) ^ ((row & 7) << 4);
        short8 bfr = *(const short8*)((char*)Ks + row * 512 + colB);
        accs[n] = mfma16(qf[kk], bfr, accs[n]);
      }

    // defer-max online softmax (exp2 domain, per-lane l partials)
    float mloc[4];
    bool need = false;
#pragma unroll
    for (int r = 0; r < 4; r++) {
      mloc[r] = fmaxf(fmaxf(accs[0][r], accs[1][r]), fmaxf(accs[2][r], accs[3][r]));
      need = need || (mloc[r] > m_run[r] + THR_);
    }
    if (__any(need)) {
#pragma unroll
      for (int r = 0; r < 4; r++) {
        float mx = mloc[r];
        mx = fmaxf(mx, __shfl_xor(mx, 1));
        mx = fmaxf(mx, __shfl_xor(mx, 2));
        mx = fmaxf(mx, __shfl_xor(mx, 4));
        mx = fmaxf(mx, __shfl_xor(mx, 8));
        float mnew = fmaxf(m_run[r], mx);
        float corr = exp2f((m_run[r] - mnew) * K2_);
        m_run[r] = mnew;
        l_run[r] *= corr;
#pragma unroll
        for (int n = 0; n < 16; n++) acco[n][r] *= corr;
      }
    }
#pragma unroll
    for (int r = 0; r < 4; r++) {
      float mk = m_run[r] * K2_;
      float p0 = exp2f(fmaf(accs[0][r], K2_, -mk));
      float p1 = exp2f(fmaf(accs[1][r], K2_, -mk));
      float p2 = exp2f(fmaf(accs[2][r], K2_, -mk));
      float p3 = exp2f(fmaf(accs[3][r], K2_, -mk));
      l_run[r] += (p0 + p1) + (p2 + p3);
      int rowl = (lane >> 4) * 4 + r;
      char* pr = (char*)Psw + rowl * 128;
      int cb = (lane & 15) * 2;
      int sw = (rowl & 7) << 4;
      *(short*)(pr + (cb ^ sw)) = f2bf(p0);
      *(short*)(pr + ((cb + 32) ^ sw)) = f2bf(p1);
      *(short*)(pr + ((cb + 64) ^ sw)) = f2bf(p2);
      *(short*)(pr + ((cb + 96) ^ sw)) = f2bf(p3);
    }
    asm volatile("s_waitcnt lgkmcnt(0)" ::: "memory");

    // O += P V^T
#pragma unroll
    for (int kk2 = 0; kk2 < 2; kk2++) {
      int rowl = lane & 15;
      int colB = ((kk2 * 32 + (lane >> 4) * 8) * 2) ^ ((rowl & 7) << 4);
      short8 pa = *(const short8*)((char*)Psw + rowl * 128 + colB);
#pragma unroll
      for (int n = 0; n < 16; n++) {
        int rowc = n * 16 + (lane & 15);
        int cB = ((kk2 * 32 + (lane >> 4) * 8) * 2) ^ ((rowc & 7) << 4);
        short8 vfr = *(const short8*)((char*)Vs + rowc * 128 + cB);
        acco[n] = mfma16(pa, vfr, acco[n]);
      }
    }
  }

  // reduce l across the row's 16 lanes, store normalized partial + (m*K2, l)
  float l_tot[4], linv[4];
#pragma unroll
  for (int r = 0; r < 4; r++) {
    float lt = l_run[r];
    lt += __shfl_xor(lt, 1);
    lt += __shfl_xor(lt, 2);
    lt += __shfl_xor(lt, 4);
    lt += __shfl_xor(lt, 8);
    l_tot[r] = lt;
    linv[r] = 1.f / lt;
  }
  short* Op = half ? O1 : O0;
#pragma unroll
  for (int n = 0; n < 16; n++)
#pragma unroll
    for (int r = 0; r < 4; r++) {
      int i = i0 + w * 16 + ((lane >> 4) << 2) + r;
      int c = n * 16 + (lane & 15);
      Op[((long)b * N_ + i) * C_ + c] = f2bf(acco[n][r] * linv[r]);
    }
  if ((lane & 15) == 0) {
#pragma unroll
    for (int r = 0; r < 4; r++) {
      int i = i0 + w * 16 + ((lane >> 4) << 2) + r;
      ml[(long)half * (B_ * N_) + b * N_ + i] = make_float2(m_run[r] * K2_, l_tot[r]);
    }
  }
}

// ---------------- merge the two j-halves ----------------
__global__ __launch_bounds__(256) void combine_halves(const short* __restrict__ O0,
                                                      const short* __restrict__ O1,
                                                      const float2* __restrict__ ml,
                                                      short* __restrict__ hT) {
  int idx = blockIdx.x * 256 + threadIdx.x;    // 16384 rows * 32 chunks
  int row = idx >> 5, c0 = (idx & 31) * 8;
  float2 a = ml[row], bb = ml[B_ * N_ + row];
  float m = fmaxf(a.x, bb.x);
  float w0 = a.y * exp2f(a.x - m);
  float w1 = bb.y * exp2f(bb.x - m);
  float inv = 1.f / (w0 + w1);
  w0 *= inv; w1 *= inv;
  short8 u = *(const short8*)(O0 + (long)row * 256 + c0);
  short8 v = *(const short8*)(O1 + (long)row * 256 + c0);
  short8 o;
#pragma unroll
  for (int j = 0; j < 8; j++) o[j] = f2bf(w0 * bf2f(u[j]) + w1 * bf2f(v[j]));
  *(short8*)(hT + (long)row * 256 + c0) = o;
}

// ---------------- launch ----------------
extern "C" void kernel_launch(void* const* d_in, const int* in_sizes, int n_in,
                              void* d_out, int out_size, void* d_ws, size_t ws_size,
                              hipStream_t stream) {
  const float* x = (const float*)d_in[0];
  const float* gamma = (const float*)d_in[1];
  const float* beta = (const float*)d_in[2];
  const float* wq = (const float*)d_in[3];
  const float* bq = (const float*)d_in[4];
  const float* wk = (const float*)d_in[5];
  const float* bk = (const float*)d_in[6];
  const float* wv = (const float*)d_in[7];
  const float* bv = (const float*)d_in[8];
  const float* wp = (const float*)d_in[9];
  const float* bp = (const float*)d_in[10];

  char* ws = (char*)d_ws;
  short* hn = (short*)ws;                                   // 8MB: hn, then Opart0, then hT
  short* qT = (short*)(ws + (size_t)8 * 1024 * 1024);
  short* kT = (short*)(ws + (size_t)16 * 1024 * 1024);
  short* vb = (short*)(ws + (size_t)24 * 1024 * 1024);
  short* wqkv = (short*)(ws + (size_t)32 * 1024 * 1024);    // [768][256]
  short* wpb = wqkv + 3 * 65536;                            // [256][256]
  float* stats = (float*)(ws + (size_t)33 * 1024 * 1024);
  float2* ml = (float2*)(ws + (size_t)33 * 1024 * 1024 + 1024);  // 2*16384 float2
  short* O1 = (short*)d_out;                                // scratch; overwritten by gemm_proj

  gn_stats<<<64, 256, 0, stream>>>(x, stats);
  gn_norm<<<dim3(16, 16, 4), 256, 0, stream>>>(x, gamma, beta, stats, hn);
  cast_w<<<1024, 256, 0, stream>>>(wq, wk, wv, wp, wqkv);

  gemm_qkv<<<dim3(6, 32, 4), 256, 0, stream>>>(hn, wqkv, bq, bk, bv, qT, kT, vb);

  attn_kernel<<<dim3(64, 4, 2), 256, 0, stream>>>(qT, kT, vb, hn /*O0*/, O1, ml);
  combine_halves<<<2048, 256, 0, stream>>>(hn, O1, ml, hn /*hT in-place*/);

  gemm_proj<<<dim3(32, 2, 4), 256, 0, stream>>>(wpb, hn, bp, x, (float*)d_out);
}

// Round 3
// 204.890 us; speedup vs baseline: 1.5260x; 1.4591x over previous
//
#include <hip/hip_runtime.h>

#define B_ 4
#define C_ 256
#define N_ 4096
#define K2_ 0.09016844f   /* 0.0625 * log2(e) */
#define THR_ 64.0f        /* defer-max threshold, raw-score units: p <= 2^(64*K2) ~ 55 */

typedef __attribute__((ext_vector_type(8))) short short8;
typedef __attribute__((ext_vector_type(4))) float f32x4;
typedef __attribute__((ext_vector_type(16))) float f32x16;
typedef __attribute__((ext_vector_type(4))) unsigned int uint4v;

static __device__ __forceinline__ short f2bf(float f) {
  union { float f; unsigned u; } v; v.f = f;
  unsigned r = v.u + 0x7FFFu + ((v.u >> 16) & 1u);
  return (short)(r >> 16);
}
static __device__ __forceinline__ float bf2f(short s) {
  union { unsigned u; float f; } v; v.u = ((unsigned)(unsigned short)s) << 16;
  return v.f;
}
static __device__ __forceinline__ f32x4 mfma16(short8 a, short8 b, f32x4 c) {
  return __builtin_amdgcn_mfma_f32_16x16x32_bf16(a, b, c, 0, 0, 0);
}
static __device__ __forceinline__ f32x16 mfma32(short8 a, short8 b, f32x16 c) {
  return __builtin_amdgcn_mfma_f32_32x32x16_bf16(a, b, c, 0, 0, 0);
}
static __device__ __forceinline__ unsigned cvtpk(float lo, float hi) {
  unsigned r;
  asm("v_cvt_pk_bf16_f32 %0, %1, %2" : "=v"(r) : "v"(lo), "v"(hi));
  return r;
}
static __device__ __forceinline__ void plswap(unsigned& a, unsigned& b) {
  // new a = (a.lo, b.lo_old); new b = (a.hi_old, b.hi)
  asm volatile("v_permlane32_swap_b32 %0, %1" : "+v"(a), "+v"(b));
}
static __device__ __forceinline__ void gload16(const void* g, void* l) {
  __builtin_amdgcn_global_load_lds(
      (const __attribute__((address_space(1))) unsigned int*)g,
      (__attribute__((address_space(3))) unsigned int*)l, 16, 0, 0);
}

// ---------------- GroupNorm stats (split 4-way per group) ----------------
__global__ __launch_bounds__(256) void gn_stats1(const float* __restrict__ x,
                                                 float2* __restrict__ part) {
  int bg = blockIdx.x >> 2, ch = blockIdx.x & 3;
  const float* xp = x + (long)bg * 65536 + ch * 16384;
  int t = threadIdx.x, lane = t & 63, w = t >> 6;
  float s = 0.f, ss = 0.f;
  for (int e = t * 4; e < 16384; e += 1024) {
    f32x4 v = *(const f32x4*)(xp + e);
    s += (v[0] + v[1]) + (v[2] + v[3]);
    ss += (v[0] * v[0] + v[1] * v[1]) + (v[2] * v[2] + v[3] * v[3]);
  }
  for (int off = 1; off < 64; off <<= 1) {
    s += __shfl_xor(s, off);
    ss += __shfl_xor(ss, off);
  }
  __shared__ float rs[4], rq[4];
  if (lane == 0) { rs[w] = s; rq[w] = ss; }
  __syncthreads();
  if (t == 0)
    part[blockIdx.x] = make_float2((rs[0] + rs[1]) + (rs[2] + rs[3]),
                                   (rq[0] + rq[1]) + (rq[2] + rq[3]));
}

// writes hn transposed: hn[b][i][c] bf16
__global__ __launch_bounds__(256) void gn_norm(const float* __restrict__ x,
                                               const float* __restrict__ gamma,
                                               const float* __restrict__ beta,
                                               const float2* __restrict__ part,
                                               short* __restrict__ hn) {
  int ic = blockIdx.x, g = blockIdx.y, b = blockIdx.z;
  int bg = b * 16 + g;
  float2 q0 = part[bg * 4], q1 = part[bg * 4 + 1], q2 = part[bg * 4 + 2], q3 = part[bg * 4 + 3];
  float s = (q0.x + q1.x) + (q2.x + q3.x);
  float ss = (q0.y + q1.y) + (q2.y + q3.y);
  float mean = s * (1.f / 65536.f);
  float rstd = rsqrtf(ss * (1.f / 65536.f) - mean * mean + 1e-6f);
  int t = threadIdx.x;
  int i = ic * 256 + t;
  __shared__ short Ls[16][256];
#pragma unroll
  for (int cl = 0; cl < 16; cl++) {
    int c = g * 16 + cl;
    float v = x[((long)(b * 256 + c)) * N_ + i];
    Ls[cl][t] = f2bf((v - mean) * rstd * gamma[c] + beta[c]);
  }
  __syncthreads();
  short8 v0, v1;
#pragma unroll
  for (int q = 0; q < 8; q++) { v0[q] = Ls[q][t]; v1[q] = Ls[8 + q][t]; }
  short* dst = hn + ((long)b * N_ + ic * 256 + t) * C_ + g * 16;
  *(short8*)dst = v0;
  *(short8*)(dst + 8) = v1;
}

// ---------------- weight cast ----------------
__global__ __launch_bounds__(256) void cast_w(const float* __restrict__ wq,
                                              const float* __restrict__ wk,
                                              const float* __restrict__ wv,
                                              const float* __restrict__ wp,
                                              short* __restrict__ out) {
  int idx = blockIdx.x * 256 + threadIdx.x;
  int which = idx >> 16, e = idx & 65535;
  const float* src = which == 0 ? wq : which == 1 ? wk : which == 2 ? wv : wp;
  out[(which << 16) + e] = f2bf(src[e]);
}

// ---------------- fused QKV GEMM (2-phase dbuf) ----------------
__global__ __launch_bounds__(256) void gemm_qkv(const short* __restrict__ hn,
                                                const short* __restrict__ wqkv,
                                                const float* __restrict__ bq,
                                                const float* __restrict__ bk,
                                                const float* __restrict__ bv,
                                                short* __restrict__ qT,
                                                short* __restrict__ kT,
                                                short* __restrict__ vbM) {
  __shared__ __align__(16) short As[2][128 * 32];
  __shared__ __align__(16) short Bs[2][128 * 32];
  const int bz = blockIdx.z;
  const int n0 = blockIdx.x * 128;   // within 768
  const int m0 = blockIdx.y * 128;   // within 4096
  const int t = threadIdx.x, lane = t & 63, w = t >> 6;
  const int wm = (w >> 1) * 64, wn = (w & 1) * 64;
  const short* Ab = hn + (long)bz * N_ * C_;
  f32x4 acc[4][4];
#pragma unroll
  for (int m = 0; m < 4; m++)
#pragma unroll
    for (int n = 0; n < 4; n++) acc[m][n] = (f32x4)0.f;
  const int g16 = (lane >> 4) * 16;

  auto stage = [&](int kt8, int buf) {
    int kt = kt8 * 32;
#pragma unroll
    for (int s = 0; s < 2; s++) {
      int q = w * 2 + s;
      int flat = q * 1024 + lane * 16;
      int row = flat >> 6, c = flat & 63;
      int cs = c ^ ((row & 3) << 4);
      gload16((const char*)Ab + ((long)(m0 + row) * 256 + kt) * 2 + cs, (char*)As[buf] + flat);
      gload16((const char*)wqkv + ((long)(n0 + row) * 256 + kt) * 2 + cs, (char*)Bs[buf] + flat);
    }
  };

  stage(0, 0);
  __syncthreads();
  for (int kt8 = 0; kt8 < 8; kt8++) {
    int cur = kt8 & 1;
    if (kt8 < 7) stage(kt8 + 1, cur ^ 1);
    short8 af[4], bf[4];
#pragma unroll
    for (int m = 0; m < 4; m++) {
      int row = wm + m * 16 + (lane & 15);
      af[m] = *(const short8*)(&As[cur][0] + row * 32 + ((g16 ^ ((row & 3) << 4)) >> 1));
    }
#pragma unroll
    for (int n = 0; n < 4; n++) {
      int row = wn + n * 16 + (lane & 15);
      bf[n] = *(const short8*)(&Bs[cur][0] + row * 32 + ((g16 ^ ((row & 3) << 4)) >> 1));
    }
    __builtin_amdgcn_s_setprio(1);
#pragma unroll
    for (int m = 0; m < 4; m++)
#pragma unroll
      for (int n = 0; n < 4; n++) acc[m][n] = mfma16(af[m], bf[n], acc[m][n]);
    __builtin_amdgcn_s_setprio(0);
    __syncthreads();
  }

  int seg = n0 >> 8;
  const float* bias = seg == 0 ? bq : seg == 1 ? bk : bv;
#pragma unroll
  for (int m = 0; m < 4; m++)
#pragma unroll
    for (int n = 0; n < 4; n++)
#pragma unroll
      for (int r = 0; r < 4; r++) {
        int row = m0 + wm + m * 16 + ((lane >> 4) << 2) + r;
        int colg = n0 + wn + n * 16 + (lane & 15);
        int coll = colg & 255;
        float vv = acc[m][n][r] + bias[coll];
        if (seg == 2) vbM[(long)bz * N_ * C_ + (long)coll * N_ + row] = f2bf(vv);
        else (seg == 0 ? qT : kT)[(long)bz * N_ * C_ + (long)row * 256 + coll] = f2bf(vv);
      }
}

// ---------------- output projection GEMM (2-phase dbuf, +bias row, +residual) ---
__global__ __launch_bounds__(256) void gemm_proj(const short* __restrict__ wp,
                                                 const short* __restrict__ hT,
                                                 const float* __restrict__ bp,
                                                 const float* __restrict__ x,
                                                 float* __restrict__ out) {
  __shared__ __align__(16) short As[2][128 * 32];
  __shared__ __align__(16) short Bs[2][128 * 32];
  const int bz = blockIdx.z;
  const int n0 = blockIdx.x * 128;   // pixels
  const int m0 = blockIdx.y * 128;   // channels
  const int t = threadIdx.x, lane = t & 63, w = t >> 6;
  const int wm = (w >> 1) * 64, wn = (w & 1) * 64;
  const short* Bb = hT + (long)bz * N_ * C_;
  f32x4 acc[4][4];
#pragma unroll
  for (int m = 0; m < 4; m++)
#pragma unroll
    for (int n = 0; n < 4; n++) acc[m][n] = (f32x4)0.f;
  const int g16 = (lane >> 4) * 16;

  auto stage = [&](int kt8, int buf) {
    int kt = kt8 * 32;
#pragma unroll
    for (int s = 0; s < 2; s++) {
      int q = w * 2 + s;
      int flat = q * 1024 + lane * 16;
      int row = flat >> 6, c = flat & 63;
      int cs = c ^ ((row & 3) << 4);
      gload16((const char*)wp + ((long)(m0 + row) * 256 + kt) * 2 + cs, (char*)As[buf] + flat);
      gload16((const char*)Bb + ((long)(n0 + row) * 256 + kt) * 2 + cs, (char*)Bs[buf] + flat);
    }
  };

  stage(0, 0);
  __syncthreads();
  for (int kt8 = 0; kt8 < 8; kt8++) {
    int cur = kt8 & 1;
    if (kt8 < 7) stage(kt8 + 1, cur ^ 1);
    short8 af[4], bf[4];
#pragma unroll
    for (int m = 0; m < 4; m++) {
      int row = wm + m * 16 + (lane & 15);
      af[m] = *(const short8*)(&As[cur][0] + row * 32 + ((g16 ^ ((row & 3) << 4)) >> 1));
    }
#pragma unroll
    for (int n = 0; n < 4; n++) {
      int row = wn + n * 16 + (lane & 15);
      bf[n] = *(const short8*)(&Bs[cur][0] + row * 32 + ((g16 ^ ((row & 3) << 4)) >> 1));
    }
    __builtin_amdgcn_s_setprio(1);
#pragma unroll
    for (int m = 0; m < 4; m++)
#pragma unroll
      for (int n = 0; n < 4; n++) acc[m][n] = mfma16(af[m], bf[n], acc[m][n]);
    __builtin_amdgcn_s_setprio(0);
    __syncthreads();
  }

#pragma unroll
  for (int m = 0; m < 4; m++)
#pragma unroll
    for (int n = 0; n < 4; n++)
#pragma unroll
      for (int r = 0; r < 4; r++) {
        int row = m0 + wm + m * 16 + ((lane >> 4) << 2) + r;   // channel
        int col = n0 + wn + n * 16 + (lane & 15);              // pixel
        long idx = (long)bz * N_ * C_ + (long)row * N_ + col;
        out[idx] = acc[m][n][r] + bp[row] + x[idx];
      }
}

// ---------------- flash attention: 32x32 swapped-QK, in-register P ----------
// qT,kT: [B][N][C] bf16 ; vM: [B][C][N] bf16 ; partials: [B][N][C] bf16 per split
__global__ __launch_bounds__(256, 1) void attn_kernel(
    const short* __restrict__ qT, const short* __restrict__ kT,
    const short* __restrict__ vM, short* __restrict__ P0, short* __restrict__ P1,
    short* __restrict__ P2, short* __restrict__ P3, float2* __restrict__ ml, int S) {
  __shared__ __align__(16) char kv[2][65536];   // per buf: K tile 32KB @0, V tile 32KB @32768
  __shared__ float cbr[4][32];

  const int nwg = 128 * S;
  const int id = blockIdx.x;
  const int nid = (id & 7) * (nwg >> 3) + (id >> 3);   // XCD-contiguous remap (bijective)
  const int itile = nid & 31;
  const int bjs = nid >> 5;
  const int js = bjs & (S - 1);
  const int b = bjs / S;

  const int t = threadIdx.x, lane = t & 63, w = t >> 6;
  const int hi = lane >> 5, li = lane & 31;
  const int hi16 = hi * 16;
  const long bNC = (long)b * N_ * C_;
  const short* qb = qT + bNC;
  const char* kb = (const char*)(kT + bNC);
  const char* vb = (const char*)(vM + bNC);
  const int i0 = itile * 128 + w * 32;
  const int jbase = js * (N_ / S);
  const int NIT = (N_ / S) / 64;

  // Q b-frags: qf[s] = Q[i0+li][s*16 + hi*8 .. +8]
  short8 qf[16];
  {
    const short* qp = qb + (long)(i0 + li) * C_ + hi * 8;
#pragma unroll
    for (int s = 0; s < 16; s++) qf[s] = *(const short8*)(qp + s * 16);
  }

  f32x16 acco[8];
#pragma unroll
  for (int cb = 0; cb < 8; cb++) acco[cb] = (f32x16)0.f;
  float m_run = -3e38f, l_run = 0.f;

  auto stage = [&](int it, int buf) {
    const int j0 = jbase + it * 64;
    char* Kd = kv[buf];
    char* Vd = kv[buf] + 32768;
#pragma unroll
    for (int p = 0; p < 8; p++) {
      int flat = p * 4096 + t * 16;
      int rk = flat >> 9, ck = flat & 511;
      gload16(kb + (long)(j0 + rk) * 512 + (ck ^ ((rk & 7) << 4)), Kd + flat);
    }
#pragma unroll
    for (int p = 0; p < 8; p++) {
      int flat = p * 4096 + t * 16;
      int rv = flat >> 7, cv = flat & 127;
      gload16(vb + (long)rv * (N_ * 2) + (long)j0 * 2 + (cv ^ ((rv & 7) << 4)), Vd + flat);
    }
  };

  stage(0, 0);
  __syncthreads();

  for (int it = 0; it < NIT; it++) {
    const int cur = it & 1;
    if (it + 1 < NIT) stage(it + 1, cur ^ 1);
    const char* Kb = kv[cur];
    const char* Vb = kv[cur] + 32768;

#pragma unroll
    for (int jb = 0; jb < 2; jb++) {
      // S^T = K * Q^T : lane holds S[i=li][16 j-values]
      f32x16 accs = (f32x16)0.f;
      const int krow = jb * 32 + li;
      const char* Kr = Kb + krow * 512;
      const int ksw = (krow & 7) << 4;
      __builtin_amdgcn_s_setprio(1);
#pragma unroll
      for (int s = 0; s < 16; s++) {
        short8 kf = *(const short8*)(Kr + ((s * 32 + hi16) ^ ksw));
        accs = mfma32(kf, qf[s], accs);
      }
      __builtin_amdgcn_s_setprio(0);

      // lane-local softmax over 16 j's, combine with hi-partner
      float pmax = accs[0];
#pragma unroll
      for (int r = 1; r < 16; r++) pmax = fmaxf(pmax, accs[r]);
      pmax = fmaxf(pmax, __shfl_xor(pmax, 32));
      if (__any(pmax > m_run + THR_)) {
        float mnew = fmaxf(m_run, pmax);
        float corr = exp2f((m_run - mnew) * K2_);
        m_run = mnew;
        l_run *= corr;
        if (lane < 32) cbr[w][li] = corr;
        asm volatile("s_waitcnt lgkmcnt(0)" ::: "memory");
        f32x4 c4[4];
#pragma unroll
        for (int g = 0; g < 4; g++) c4[g] = *(const f32x4*)&cbr[w][g * 8 + hi * 4];
#pragma unroll
        for (int cb = 0; cb < 8; cb++)
#pragma unroll
          for (int r = 0; r < 16; r++) acco[cb][r] *= c4[r >> 2][r & 3];
      }
      const float mk = m_run * K2_;
      float p[16];
#pragma unroll
      for (int r = 0; r < 16; r++) {
        p[r] = exp2f(fmaf(accs[r], K2_, -mk));
        l_run += p[r];
      }

      // pack P to bf16 PV A-frags via cvt_pk + permlane32_swap (T12)
      unsigned a0 = cvtpk(p[0], p[1]), b0 = cvtpk(p[4], p[5]);
      unsigned a1 = cvtpk(p[2], p[3]), b1 = cvtpk(p[6], p[7]);
      plswap(a0, b0); plswap(a1, b1);
      uint4v u0 = {a0, a1, b0, b1};
      short8 pa0 = __builtin_bit_cast(short8, u0);
      unsigned a2 = cvtpk(p[8], p[9]), b2 = cvtpk(p[12], p[13]);
      unsigned a3 = cvtpk(p[10], p[11]), b3 = cvtpk(p[14], p[15]);
      plswap(a2, b2); plswap(a3, b3);
      uint4v u1 = {a2, a3, b2, b3};
      short8 pa1 = __builtin_bit_cast(short8, u1);

      // O += P * V^T
      const int jcb0 = jb * 64 + hi16;
      __builtin_amdgcn_s_setprio(1);
#pragma unroll
      for (int cb = 0; cb < 8; cb++) {
        const int vrow = cb * 32 + li;
        const char* Vr = Vb + vrow * 128;
        const int vsw = (vrow & 7) << 4;
        short8 vf0 = *(const short8*)(Vr + (jcb0 ^ vsw));
        acco[cb] = mfma32(pa0, vf0, acco[cb]);
        short8 vf1 = *(const short8*)(Vr + ((jcb0 + 32) ^ vsw));
        acco[cb] = mfma32(pa1, vf1, acco[cb]);
      }
      __builtin_amdgcn_s_setprio(0);
    }
    __syncthreads();
  }

  // finalize: total l, broadcast 1/l per row, store normalized partial + (m,l)
  l_run += __shfl_xor(l_run, 32);
  float inv = 1.f / l_run;
  if (lane < 32) cbr[w][li] = inv;
  asm volatile("s_waitcnt lgkmcnt(0)" ::: "memory");
  f32x4 i4[4];
#pragma unroll
  for (int g = 0; g < 4; g++) i4[g] = *(const f32x4*)&cbr[w][g * 8 + hi * 4];

  short* Op = (js == 0) ? P0 : (js == 1) ? P1 : (js == 2) ? P2 : P3;
  short* ob = Op + bNC;
#pragma unroll
  for (int cb = 0; cb < 8; cb++)
#pragma unroll
    for (int r = 0; r < 16; r++) {
      int i = i0 + (r & 3) + 8 * (r >> 2) + 4 * hi;
      ob[(long)i * C_ + cb * 32 + li] = f2bf(acco[cb][r] * i4[r >> 2][r & 3]);
    }
  if (lane < 32)
    ml[(long)js * (B_ * N_) + b * N_ + i0 + li] = make_float2(m_run * K2_, l_run);
}

// ---------------- merge the split-j partials ----------------
__global__ __launch_bounds__(256) void combine(const short* __restrict__ p0,
                                               const short* __restrict__ p1,
                                               const short* __restrict__ p2,
                                               const short* __restrict__ p3,
                                               const float2* __restrict__ ml, int S,
                                               short* __restrict__ hT) {
  int idx = blockIdx.x * 256 + threadIdx.x;    // 16384 rows * 32 chunks
  int row = idx >> 5, c0 = (idx & 31) * 8;
  float2 m0 = ml[row], m1 = ml[16384 + row];
  float mmax = fmaxf(m0.x, m1.x);
  float2 m2 = m0, m3 = m0;
  if (S == 4) {
    m2 = ml[2 * 16384 + row];
    m3 = ml[3 * 16384 + row];
    mmax = fmaxf(mmax, fmaxf(m2.x, m3.x));
  }
  float w0 = m0.y * exp2f(m0.x - mmax);
  float w1 = m1.y * exp2f(m1.x - mmax);
  float w2 = 0.f, w3 = 0.f;
  if (S == 4) { w2 = m2.y * exp2f(m2.x - mmax); w3 = m3.y * exp2f(m3.x - mmax); }
  float inv = 1.f / ((w0 + w1) + (w2 + w3));
  w0 *= inv; w1 *= inv; w2 *= inv; w3 *= inv;
  long off = (long)row * 256 + c0;
  short8 u0 = *(const short8*)(p0 + off);
  short8 u1 = *(const short8*)(p1 + off);
  short8 o;
  if (S == 4) {
    short8 u2 = *(const short8*)(p2 + off);
    short8 u3 = *(const short8*)(p3 + off);
#pragma unroll
    for (int j = 0; j < 8; j++)
      o[j] = f2bf((w0 * bf2f(u0[j]) + w1 * bf2f(u1[j])) +
                  (w2 * bf2f(u2[j]) + w3 * bf2f(u3[j])));
  } else {
#pragma unroll
    for (int j = 0; j < 8; j++) o[j] = f2bf(w0 * bf2f(u0[j]) + w1 * bf2f(u1[j]));
  }
  *(short8*)(hT + off) = o;
}

// ---------------- launch ----------------
extern "C" void kernel_launch(void* const* d_in, const int* in_sizes, int n_in,
                              void* d_out, int out_size, void* d_ws, size_t ws_size,
                              hipStream_t stream) {
  const float* x = (const float*)d_in[0];
  const float* gamma = (const float*)d_in[1];
  const float* beta = (const float*)d_in[2];
  const float* wq = (const float*)d_in[3];
  const float* bq = (const float*)d_in[4];
  const float* wk = (const float*)d_in[5];
  const float* bk = (const float*)d_in[6];
  const float* wv = (const float*)d_in[7];
  const float* bv = (const float*)d_in[8];
  const float* wp = (const float*)d_in[9];
  const float* bp = (const float*)d_in[10];

  char* ws = (char*)d_ws;
  short* hn = (short*)ws;                                   // 8MB: hn -> partial0 -> hT
  short* qT = (short*)(ws + (size_t)8388608);
  short* kT = (short*)(ws + (size_t)16777216);
  short* vb = (short*)(ws + (size_t)25165824);
  short* wqkv = (short*)(ws + (size_t)33554432);            // [768][256]
  short* wpb = wqkv + 3 * 65536;                            // [256][256]
  float2* part = (float2*)(ws + (size_t)34078720);          // 256 float2
  float2* ml = (float2*)(ws + (size_t)34080768);            // up to 4*16384 float2 (512KB)
  short* P1 = (short*)d_out;                                // 8.39MB (scratch)
  short* P2 = (short*)d_out + 4194304;                      // 8.39MB (scratch)
  short* P3 = (short*)(ws + (size_t)34605056);              // 8.39MB if ws allows
  const int S = (ws_size >= (size_t)43000000) ? 4 : 2;
  if (S == 2) { P2 = hn; P3 = hn; }                         // unused for S=2

  gn_stats1<<<256, 256, 0, stream>>>(x, part);
  gn_norm<<<dim3(16, 16, 4), 256, 0, stream>>>(x, gamma, beta, part, hn);
  cast_w<<<1024, 256, 0, stream>>>(wq, wk, wv, wp, wqkv);

  gemm_qkv<<<dim3(6, 32, 4), 256, 0, stream>>>(hn, wqkv, bq, bk, bv, qT, kT, vb);

  attn_kernel<<<dim3(128 * S), 256, 0, stream>>>(qT, kT, vb, hn /*P0*/, P1, P2, P3, ml, S);
  combine<<<2048, 256, 0, stream>>>(hn, P1, P2, P3, ml, S, hn /*hT in place*/);

  gemm_proj<<<dim3(32, 2, 4), 256, 0, stream>>>(wpb, hn, bp, x, (float*)d_out);
}

// Round 4
// 184.099 us; speedup vs baseline: 1.6984x; 1.1129x over previous
//
#include <hip/hip_runtime.h>

#define B_ 4
#define C_ 256
#define N_ 4096
#define K2_ 0.09016844f   /* 0.0625 * log2(e) */
#define THR_ 64.0f        /* defer-max threshold, raw-score units */

typedef __attribute__((ext_vector_type(8))) short short8;
typedef __attribute__((ext_vector_type(4))) float f32x4;
typedef __attribute__((ext_vector_type(16))) float f32x16;
typedef __attribute__((ext_vector_type(4))) unsigned int uint4v;

static __device__ __forceinline__ short f2bf(float f) {
  union { float f; unsigned u; } v; v.f = f;
  unsigned r = v.u + 0x7FFFu + ((v.u >> 16) & 1u);
  return (short)(r >> 16);
}
static __device__ __forceinline__ float bf2f(short s) {
  union { unsigned u; float f; } v; v.u = ((unsigned)(unsigned short)s) << 16;
  return v.f;
}
static __device__ __forceinline__ f32x4 mfma16(short8 a, short8 b, f32x4 c) {
  return __builtin_amdgcn_mfma_f32_16x16x32_bf16(a, b, c, 0, 0, 0);
}
static __device__ __forceinline__ f32x16 mfma32(short8 a, short8 b, f32x16 c) {
  return __builtin_amdgcn_mfma_f32_32x32x16_bf16(a, b, c, 0, 0, 0);
}
static __device__ __forceinline__ unsigned cvtpk(float lo, float hi) {
  unsigned r;
  asm("v_cvt_pk_bf16_f32 %0, %1, %2" : "=v"(r) : "v"(lo), "v"(hi));
  return r;
}
static __device__ __forceinline__ void plswap(unsigned& a, unsigned& b) {
  asm volatile("v_permlane32_swap_b32 %0, %1" : "+v"(a), "+v"(b));
}
static __device__ __forceinline__ void gload16(const void* g, void* l) {
  __builtin_amdgcn_global_load_lds(
      (const __attribute__((address_space(1))) unsigned int*)g,
      (__attribute__((address_space(3))) unsigned int*)l, 16, 0, 0);
}

// ---------------- GroupNorm stats (split 4-way per group) ----------------
__global__ __launch_bounds__(256) void gn_stats1(const float* __restrict__ x,
                                                 float2* __restrict__ part) {
  int bg = blockIdx.x >> 2, ch = blockIdx.x & 3;
  const float* xp = x + (long)bg * 65536 + ch * 16384;
  int t = threadIdx.x, lane = t & 63, w = t >> 6;
  float s = 0.f, ss = 0.f;
  for (int e = t * 4; e < 16384; e += 1024) {
    f32x4 v = *(const f32x4*)(xp + e);
    s += (v[0] + v[1]) + (v[2] + v[3]);
    ss += (v[0] * v[0] + v[1] * v[1]) + (v[2] * v[2] + v[3] * v[3]);
  }
  for (int off = 1; off < 64; off <<= 1) {
    s += __shfl_xor(s, off);
    ss += __shfl_xor(ss, off);
  }
  __shared__ float rs[4], rq[4];
  if (lane == 0) { rs[w] = s; rq[w] = ss; }
  __syncthreads();
  if (t == 0)
    part[blockIdx.x] = make_float2((rs[0] + rs[1]) + (rs[2] + rs[3]),
                                   (rq[0] + rq[1]) + (rq[2] + rq[3]));
}

// writes hn transposed: hn[b][i][c] bf16
__global__ __launch_bounds__(256) void gn_norm(const float* __restrict__ x,
                                               const float* __restrict__ gamma,
                                               const float* __restrict__ beta,
                                               const float2* __restrict__ part,
                                               short* __restrict__ hn) {
  int ic = blockIdx.x, g = blockIdx.y, b = blockIdx.z;
  int bg = b * 16 + g;
  float2 q0 = part[bg * 4], q1 = part[bg * 4 + 1], q2 = part[bg * 4 + 2], q3 = part[bg * 4 + 3];
  float s = (q0.x + q1.x) + (q2.x + q3.x);
  float ss = (q0.y + q1.y) + (q2.y + q3.y);
  float mean = s * (1.f / 65536.f);
  float rstd = rsqrtf(ss * (1.f / 65536.f) - mean * mean + 1e-6f);
  int t = threadIdx.x;
  int i = ic * 256 + t;
  __shared__ short Ls[16][256];
#pragma unroll
  for (int cl = 0; cl < 16; cl++) {
    int c = g * 16 + cl;
    float v = x[((long)(b * 256 + c)) * N_ + i];
    Ls[cl][t] = f2bf((v - mean) * rstd * gamma[c] + beta[c]);
  }
  __syncthreads();
  short8 v0, v1;
#pragma unroll
  for (int q = 0; q < 8; q++) { v0[q] = Ls[q][t]; v1[q] = Ls[8 + q][t]; }
  short* dst = hn + ((long)b * N_ + ic * 256 + t) * C_ + g * 16;
  *(short8*)dst = v0;
  *(short8*)(dst + 8) = v1;
}

// ---------------- weight cast ----------------
__global__ __launch_bounds__(256) void cast_w(const float* __restrict__ wq,
                                              const float* __restrict__ wk,
                                              const float* __restrict__ wv,
                                              const float* __restrict__ wp,
                                              short* __restrict__ out) {
  int idx = blockIdx.x * 256 + threadIdx.x;
  int which = idx >> 16, e = idx & 65535;
  const float* src = which == 0 ? wq : which == 1 ? wk : which == 2 ? wv : wp;
  out[(which << 16) + e] = f2bf(src[e]);
}

// ---------------- fused QKV GEMM (2-phase dbuf) ----------------
__global__ __launch_bounds__(256) void gemm_qkv(const short* __restrict__ hn,
                                                const short* __restrict__ wqkv,
                                                const float* __restrict__ bq,
                                                const float* __restrict__ bk,
                                                const float* __restrict__ bv,
                                                short* __restrict__ qT,
                                                short* __restrict__ kT,
                                                short* __restrict__ vbM) {
  __shared__ __align__(16) short As[2][128 * 32];
  __shared__ __align__(16) short Bs[2][128 * 32];
  const int bz = blockIdx.z;
  const int n0 = blockIdx.x * 128;   // within 768
  const int m0 = blockIdx.y * 128;   // within 4096
  const int t = threadIdx.x, lane = t & 63, w = t >> 6;
  const int wm = (w >> 1) * 64, wn = (w & 1) * 64;
  const short* Ab = hn + (long)bz * N_ * C_;
  f32x4 acc[4][4];
#pragma unroll
  for (int m = 0; m < 4; m++)
#pragma unroll
    for (int n = 0; n < 4; n++) acc[m][n] = (f32x4)0.f;
  const int g16 = (lane >> 4) * 16;

  auto stage = [&](int kt8, int buf) {
    int kt = kt8 * 32;
#pragma unroll
    for (int s = 0; s < 2; s++) {
      int q = w * 2 + s;
      int flat = q * 1024 + lane * 16;
      int row = flat >> 6, c = flat & 63;
      int cs = c ^ ((row & 3) << 4);
      gload16((const char*)Ab + ((long)(m0 + row) * 256 + kt) * 2 + cs, (char*)As[buf] + flat);
      gload16((const char*)wqkv + ((long)(n0 + row) * 256 + kt) * 2 + cs, (char*)Bs[buf] + flat);
    }
  };

  stage(0, 0);
  __syncthreads();
  for (int kt8 = 0; kt8 < 8; kt8++) {
    int cur = kt8 & 1;
    if (kt8 < 7) stage(kt8 + 1, cur ^ 1);
    short8 af[4], bf[4];
#pragma unroll
    for (int m = 0; m < 4; m++) {
      int row = wm + m * 16 + (lane & 15);
      af[m] = *(const short8*)(&As[cur][0] + row * 32 + ((g16 ^ ((row & 3) << 4)) >> 1));
    }
#pragma unroll
    for (int n = 0; n < 4; n++) {
      int row = wn + n * 16 + (lane & 15);
      bf[n] = *(const short8*)(&Bs[cur][0] + row * 32 + ((g16 ^ ((row & 3) << 4)) >> 1));
    }
    __builtin_amdgcn_s_setprio(1);
#pragma unroll
    for (int m = 0; m < 4; m++)
#pragma unroll
      for (int n = 0; n < 4; n++) acc[m][n] = mfma16(af[m], bf[n], acc[m][n]);
    __builtin_amdgcn_s_setprio(0);
    __syncthreads();
  }

  int seg = n0 >> 8;
  const float* bias = seg == 0 ? bq : seg == 1 ? bk : bv;
#pragma unroll
  for (int m = 0; m < 4; m++)
#pragma unroll
    for (int n = 0; n < 4; n++)
#pragma unroll
      for (int r = 0; r < 4; r++) {
        int row = m0 + wm + m * 16 + ((lane >> 4) << 2) + r;
        int colg = n0 + wn + n * 16 + (lane & 15);
        int coll = colg & 255;
        float vv = acc[m][n][r] + bias[coll];
        if (seg == 2) vbM[(long)bz * N_ * C_ + (long)coll * N_ + row] = f2bf(vv);
        else (seg == 0 ? qT : kT)[(long)bz * N_ * C_ + (long)row * 256 + coll] = f2bf(vv);
      }
}

// ---------------- output projection GEMM (2-phase dbuf, +bias row, +residual) ---
__global__ __launch_bounds__(256) void gemm_proj(const short* __restrict__ wp,
                                                 const short* __restrict__ hT,
                                                 const float* __restrict__ bp,
                                                 const float* __restrict__ x,
                                                 float* __restrict__ out) {
  __shared__ __align__(16) short As[2][128 * 32];
  __shared__ __align__(16) short Bs[2][128 * 32];
  const int bz = blockIdx.z;
  const int n0 = blockIdx.x * 128;   // pixels
  const int m0 = blockIdx.y * 128;   // channels
  const int t = threadIdx.x, lane = t & 63, w = t >> 6;
  const int wm = (w >> 1) * 64, wn = (w & 1) * 64;
  const short* Bb = hT + (long)bz * N_ * C_;
  f32x4 acc[4][4];
#pragma unroll
  for (int m = 0; m < 4; m++)
#pragma unroll
    for (int n = 0; n < 4; n++) acc[m][n] = (f32x4)0.f;
  const int g16 = (lane >> 4) * 16;

  auto stage = [&](int kt8, int buf) {
    int kt = kt8 * 32;
#pragma unroll
    for (int s = 0; s < 2; s++) {
      int q = w * 2 + s;
      int flat = q * 1024 + lane * 16;
      int row = flat >> 6, c = flat & 63;
      int cs = c ^ ((row & 3) << 4);
      gload16((const char*)wp + ((long)(m0 + row) * 256 + kt) * 2 + cs, (char*)As[buf] + flat);
      gload16((const char*)Bb + ((long)(n0 + row) * 256 + kt) * 2 + cs, (char*)Bs[buf] + flat);
    }
  };

  stage(0, 0);
  __syncthreads();
  for (int kt8 = 0; kt8 < 8; kt8++) {
    int cur = kt8 & 1;
    if (kt8 < 7) stage(kt8 + 1, cur ^ 1);
    short8 af[4], bf[4];
#pragma unroll
    for (int m = 0; m < 4; m++) {
      int row = wm + m * 16 + (lane & 15);
      af[m] = *(const short8*)(&As[cur][0] + row * 32 + ((g16 ^ ((row & 3) << 4)) >> 1));
    }
#pragma unroll
    for (int n = 0; n < 4; n++) {
      int row = wn + n * 16 + (lane & 15);
      bf[n] = *(const short8*)(&Bs[cur][0] + row * 32 + ((g16 ^ ((row & 3) << 4)) >> 1));
    }
    __builtin_amdgcn_s_setprio(1);
#pragma unroll
    for (int m = 0; m < 4; m++)
#pragma unroll
      for (int n = 0; n < 4; n++) acc[m][n] = mfma16(af[m], bf[n], acc[m][n]);
    __builtin_amdgcn_s_setprio(0);
    __syncthreads();
  }

#pragma unroll
  for (int m = 0; m < 4; m++)
#pragma unroll
    for (int n = 0; n < 4; n++)
#pragma unroll
      for (int r = 0; r < 4; r++) {
        int row = m0 + wm + m * 16 + ((lane >> 4) << 2) + r;   // channel
        int col = n0 + wn + n * 16 + (lane & 15);              // pixel
        long idx = (long)bz * N_ * C_ + (long)row * N_ + col;
        out[idx] = acc[m][n][r] + bp[row] + x[idx];
      }
}

// ---------------- flash attention: 8 waves/block, 32x32 swapped-QK ----------
// qT,kT: [B][N][C] bf16 ; vM: [B][C][N] bf16 ; partials per split js
__global__ __launch_bounds__(512, 2) void attn_kernel(
    const short* __restrict__ qT, const short* __restrict__ kT,
    const short* __restrict__ vM, short* __restrict__ P0, short* __restrict__ P1,
    short* __restrict__ P2, short* __restrict__ P3, float2* __restrict__ ml, int S) {
  __shared__ __align__(16) char kv[2][65536];   // per buf: K 32KB @0, V 32KB @32768
  __shared__ float cbr[8][32];

  const int nwg = 64 * S;                       // 16 itiles x (4b x S)
  const int id = blockIdx.x;
  const int nid = (id & 7) * (nwg >> 3) + (id >> 3);   // XCD-contiguous (bijective, nwg%8==0)
  const int itile = nid & 15;
  const int bjs = nid >> 4;
  const int js = bjs % S;
  const int b = bjs / S;

  const int t = threadIdx.x, lane = t & 63, w = t >> 6;
  const int hi = lane >> 5, li = lane & 31;
  const int hi16 = hi * 16;
  const long bNC = (long)b * N_ * C_;
  const short* qb = qT + bNC;
  const char* kb = (const char*)(kT + bNC);
  const char* vb = (const char*)(vM + bNC);
  const int i0 = itile * 256 + w * 32;
  const int jbase = js * (N_ / S);
  const int NIT = (N_ / S) / 64;

  // Q b-frags: qf[s] = Q[i0+li][s*16 + hi*8 .. +8]
  short8 qf[16];
  {
    const short* qp = qb + (long)(i0 + li) * C_ + hi * 8;
#pragma unroll
    for (int s = 0; s < 16; s++) qf[s] = *(const short8*)(qp + s * 16);
  }

  f32x16 acco[8];
#pragma unroll
  for (int cb = 0; cb < 8; cb++) acco[cb] = (f32x16)0.f;
  float m_run = -3e38f, l_run = 0.f;

  auto stage = [&](int it, int buf) {
    const int j0 = jbase + it * 64;
    char* Kd = kv[buf];
    char* Vd = kv[buf] + 32768;
#pragma unroll
    for (int p = 0; p < 4; p++) {
      int flat = p * 8192 + t * 16;
      int rk = flat >> 9, ck = flat & 511;
      gload16(kb + (long)(j0 + rk) * 512 + (ck ^ ((rk & 7) << 4)), Kd + flat);
      int rv = flat >> 7, cv = flat & 127;
      gload16(vb + (long)rv * (N_ * 2) + (long)j0 * 2 + (cv ^ ((rv & 7) << 4)), Vd + flat);
    }
  };

  stage(0, 0);
  __syncthreads();

  for (int it = 0; it < NIT; it++) {
    const int cur = it & 1;
    if (it + 1 < NIT) stage(it + 1, cur ^ 1);
    const char* Kb = kv[cur];
    const char* Vb = kv[cur] + 32768;

#pragma unroll
    for (int jb = 0; jb < 2; jb++) {
      // S^T = K * Q^T : lane holds S[i=li][16 j-values]
      f32x16 accs = (f32x16)0.f;
      const int krow = jb * 32 + li;
      const char* Kr = Kb + krow * 512;
      const int ksw = (krow & 7) << 4;
      __builtin_amdgcn_s_setprio(1);
#pragma unroll
      for (int s = 0; s < 16; s++) {
        short8 kf = *(const short8*)(Kr + ((s * 32 + hi16) ^ ksw));
        accs = mfma32(kf, qf[s], accs);
      }
      __builtin_amdgcn_s_setprio(0);

      // lane-local softmax over 16 j's, combine with hi-partner
      float pmax = accs[0];
#pragma unroll
      for (int r = 1; r < 16; r++) pmax = fmaxf(pmax, accs[r]);
      pmax = fmaxf(pmax, __shfl_xor(pmax, 32));
      if (__any(pmax > m_run + THR_)) {
        float mnew = fmaxf(m_run, pmax);
        float corr = exp2f((m_run - mnew) * K2_);
        m_run = mnew;
        l_run *= corr;
        if (lane < 32) cbr[w][li] = corr;
        asm volatile("s_waitcnt lgkmcnt(0)" ::: "memory");
        f32x4 c4[4];
#pragma unroll
        for (int g = 0; g < 4; g++) c4[g] = *(const f32x4*)&cbr[w][g * 8 + hi * 4];
#pragma unroll
        for (int cb = 0; cb < 8; cb++)
#pragma unroll
          for (int r = 0; r < 16; r++) acco[cb][r] *= c4[r >> 2][r & 3];
      }
      const float mk = m_run * K2_;
      float p[16];
#pragma unroll
      for (int r = 0; r < 16; r++) {
        p[r] = exp2f(fmaf(accs[r], K2_, -mk));
        l_run += p[r];
      }

      // pack P to bf16 PV A-frags via cvt_pk + permlane32_swap (T12)
      unsigned a0 = cvtpk(p[0], p[1]), b0 = cvtpk(p[4], p[5]);
      unsigned a1 = cvtpk(p[2], p[3]), b1 = cvtpk(p[6], p[7]);
      plswap(a0, b0); plswap(a1, b1);
      uint4v u0 = {a0, a1, b0, b1};
      short8 pa0 = __builtin_bit_cast(short8, u0);
      unsigned a2 = cvtpk(p[8], p[9]), b2 = cvtpk(p[12], p[13]);
      unsigned a3 = cvtpk(p[10], p[11]), b3 = cvtpk(p[14], p[15]);
      plswap(a2, b2); plswap(a3, b3);
      uint4v u1 = {a2, a3, b2, b3};
      short8 pa1 = __builtin_bit_cast(short8, u1);

      // O += P * V^T
      const int jcb0 = jb * 64 + hi16;
      __builtin_amdgcn_s_setprio(1);
#pragma unroll
      for (int cb = 0; cb < 8; cb++) {
        const int vrow = cb * 32 + li;
        const char* Vr = Vb + vrow * 128;
        const int vsw = (vrow & 7) << 4;
        short8 vf0 = *(const short8*)(Vr + (jcb0 ^ vsw));
        acco[cb] = mfma32(pa0, vf0, acco[cb]);
        short8 vf1 = *(const short8*)(Vr + ((jcb0 + 32) ^ vsw));
        acco[cb] = mfma32(pa1, vf1, acco[cb]);
      }
      __builtin_amdgcn_s_setprio(0);
    }
    __syncthreads();
  }

  // finalize: total l, broadcast 1/l per row, store normalized partial + (m,l)
  l_run += __shfl_xor(l_run, 32);
  float inv = 1.f / l_run;
  if (lane < 32) cbr[w][li] = inv;
  asm volatile("s_waitcnt lgkmcnt(0)" ::: "memory");
  f32x4 i4[4];
#pragma unroll
  for (int g = 0; g < 4; g++) i4[g] = *(const f32x4*)&cbr[w][g * 8 + hi * 4];

  short* Op = (js == 0) ? P0 : (js == 1) ? P1 : (js == 2) ? P2 : P3;
  short* ob = Op + bNC;
#pragma unroll
  for (int cb = 0; cb < 8; cb++)
#pragma unroll
    for (int r = 0; r < 16; r++) {
      int i = i0 + (r & 3) + 8 * (r >> 2) + 4 * hi;
      ob[(long)i * C_ + cb * 32 + li] = f2bf(acco[cb][r] * i4[r >> 2][r & 3]);
    }
  if (lane < 32)
    ml[(long)js * (B_ * N_) + b * N_ + i0 + li] = make_float2(m_run * K2_, l_run);
}

// ---------------- merge the split-j partials ----------------
__global__ __launch_bounds__(256) void combine(const short* __restrict__ p0,
                                               const short* __restrict__ p1,
                                               const short* __restrict__ p2,
                                               const short* __restrict__ p3,
                                               const float2* __restrict__ ml, int S,
                                               short* __restrict__ hT) {
  int idx = blockIdx.x * 256 + threadIdx.x;    // 16384 rows * 32 chunks
  int row = idx >> 5, c0 = (idx & 31) * 8;
  float2 m0 = ml[row], m1 = ml[16384 + row];
  float mmax = fmaxf(m0.x, m1.x);
  float2 m2 = m0, m3 = m0;
  if (S == 4) {
    m2 = ml[2 * 16384 + row];
    m3 = ml[3 * 16384 + row];
    mmax = fmaxf(mmax, fmaxf(m2.x, m3.x));
  }
  float w0 = m0.y * exp2f(m0.x - mmax);
  float w1 = m1.y * exp2f(m1.x - mmax);
  float w2 = 0.f, w3 = 0.f;
  if (S == 4) { w2 = m2.y * exp2f(m2.x - mmax); w3 = m3.y * exp2f(m3.x - mmax); }
  float inv = 1.f / ((w0 + w1) + (w2 + w3));
  w0 *= inv; w1 *= inv; w2 *= inv; w3 *= inv;
  long off = (long)row * 256 + c0;
  short8 u0 = *(const short8*)(p0 + off);
  short8 u1 = *(const short8*)(p1 + off);
  short8 o;
  if (S == 4) {
    short8 u2 = *(const short8*)(p2 + off);
    short8 u3 = *(const short8*)(p3 + off);
#pragma unroll
    for (int j = 0; j < 8; j++)
      o[j] = f2bf((w0 * bf2f(u0[j]) + w1 * bf2f(u1[j])) +
                  (w2 * bf2f(u2[j]) + w3 * bf2f(u3[j])));
  } else {
#pragma unroll
    for (int j = 0; j < 8; j++) o[j] = f2bf(w0 * bf2f(u0[j]) + w1 * bf2f(u1[j]));
  }
  *(short8*)(hT + off) = o;
}

// ---------------- launch ----------------
extern "C" void kernel_launch(void* const* d_in, const int* in_sizes, int n_in,
                              void* d_out, int out_size, void* d_ws, size_t ws_size,
                              hipStream_t stream) {
  const float* x = (const float*)d_in[0];
  const float* gamma = (const float*)d_in[1];
  const float* beta = (const float*)d_in[2];
  const float* wq = (const float*)d_in[3];
  const float* bq = (const float*)d_in[4];
  const float* wk = (const float*)d_in[5];
  const float* bk = (const float*)d_in[6];
  const float* wv = (const float*)d_in[7];
  const float* bv = (const float*)d_in[8];
  const float* wp = (const float*)d_in[9];
  const float* bp = (const float*)d_in[10];

  char* ws = (char*)d_ws;
  short* hn = (short*)ws;                                   // 8MB: hn -> partial0 -> hT
  short* qT = (short*)(ws + (size_t)8388608);
  short* kT = (short*)(ws + (size_t)16777216);
  short* vb = (short*)(ws + (size_t)25165824);
  short* wqkv = (short*)(ws + (size_t)33554432);            // [768][256]
  short* wpb = wqkv + 3 * 65536;                            // [256][256]
  float2* part = (float2*)(ws + (size_t)34078720);          // 256 float2
  float2* ml = (float2*)(ws + (size_t)34080768);            // up to 4*16384 float2
  short* P1 = (short*)d_out;                                // scratch (rewritten by gemm_proj)
  short* P2 = (short*)d_out + 4194304;
  short* P3 = (short*)(ws + (size_t)34605056);
  const int S = (ws_size >= (size_t)43000000) ? 4 : 2;
  if (S == 2) { P2 = hn; P3 = hn; }

  gn_stats1<<<256, 256, 0, stream>>>(x, part);
  gn_norm<<<dim3(16, 16, 4), 256, 0, stream>>>(x, gamma, beta, part, hn);
  cast_w<<<1024, 256, 0, stream>>>(wq, wk, wv, wp, wqkv);

  gemm_qkv<<<dim3(6, 32, 4), 256, 0, stream>>>(hn, wqkv, bq, bk, bv, qT, kT, vb);

  attn_kernel<<<dim3(64 * S), 512, 0, stream>>>(qT, kT, vb, hn /*P0*/, P1, P2, P3, ml, S);
  combine<<<2048, 256, 0, stream>>>(hn, P1, P2, P3, ml, S, hn /*hT in place*/);

  gemm_proj<<<dim3(32, 2, 4), 256, 0, stream>>>(wpb, hn, bp, x, (float*)d_out);
}